// Round 12
// baseline (247.939 us; speedup 1.0000x reference)
//
#include <hip/hip_runtime.h>
#include <hip/hip_bf16.h>

// Problem constants
#define B_ROWS 16384
#define OBS_D  512
#define H_D    1024
#define N_AG   9

typedef __attribute__((ext_vector_type(8))) short short8;
typedef __attribute__((ext_vector_type(4))) float floatx4;

__device__ __forceinline__ unsigned short f_to_bf_raw(float f) {
  union { float f; unsigned u; } c; c.f = f;
  unsigned u = c.u;
  u = u + 0x7FFF + ((u >> 16) & 1);   // round-to-nearest-even
  return (unsigned short)(u >> 16);
}

// Fragment-major WEIGHT layout (B operand only; A stays row-major):
//   frag_tile = (n>>4)*KT32 + (k>>5)
//   lane      = (n&15) | (((k>>3)&3)<<4)
//   j         = k&7
// offset (bf16 units) = (frag_tile*64 + lane)*8 + j
__device__ __forceinline__ size_t frag_off(int n, int k, int KT32) {
  const int ft = (n >> 4) * KT32 + (k >> 5);
  const int ln = (n & 15) | (((k >> 3) & 3) << 4);
  return ((size_t)ft * 64 + ln) * 8 + (k & 7);
}

// ---------------------------------------------------------------------------
// Mega-prep (proven, unchanged)
// ---------------------------------------------------------------------------
__global__ __launch_bounds__(256) void prep_all(
    const float* __restrict__ obs,
    const float* __restrict__ W1, const float* __restrict__ W2,
    const float* __restrict__ Wc1, const float* __restrict__ Wt1,
    const float* __restrict__ Wk1,
    const float* __restrict__ bc1, const float* __restrict__ bt1,
    const float* __restrict__ bk1,
    const float* __restrict__ Wc2, const float* __restrict__ Wt2,
    const float* __restrict__ Wk2,
    unsigned short* __restrict__ obs_bf,
    unsigned short* __restrict__ W1f, unsigned short* __restrict__ W2f,
    unsigned short* __restrict__ WHf,
    float* __restrict__ bias2048, float* __restrict__ w2cat) {
  __shared__ float t[32][33];
  const int bx  = blockIdx.x;
  const int tid = threadIdx.x;

  if (bx < 4096) {                       // obs fp32 -> bf16, 8 elems/thread
    int i = (bx * 256 + tid) * 8;
    float4 a = *(const float4*)(obs + i);
    float4 b = *(const float4*)(obs + i + 4);
    short8 o;
    o[0] = (short)f_to_bf_raw(a.x); o[1] = (short)f_to_bf_raw(a.y);
    o[2] = (short)f_to_bf_raw(a.z); o[3] = (short)f_to_bf_raw(a.w);
    o[4] = (short)f_to_bf_raw(b.x); o[5] = (short)f_to_bf_raw(b.y);
    o[6] = (short)f_to_bf_raw(b.z); o[7] = (short)f_to_bf_raw(b.w);
    *(short8*)(obs_bf + i) = o;
    return;
  }

  const int tx = tid & 31;
  const int ty = tid >> 5;   // 0..7

  if (bx < 4608) {                       // W1 [512,1024] -> W1f (K=512,KT32=16)
    const int tt = bx - 4096;
    const int k0 = (tt & 15) * 32;
    const int n0 = (tt >> 4) * 32;
#pragma unroll
    for (int i = ty; i < 32; i += 8)
      t[i][tx] = W1[(size_t)(k0 + i) * 1024 + n0 + tx];
    __syncthreads();
#pragma unroll
    for (int i = ty; i < 32; i += 8)
      W1f[frag_off(n0 + i, k0 + tx, 16)] = f_to_bf_raw(t[tx][i]);
    return;
  }

  if (bx < 5632) {                       // W2 [1024,1024] -> W2f (KT32=32)
    const int tt = bx - 4608;
    const int k0 = (tt & 31) * 32;
    const int n0 = (tt >> 5) * 32;
#pragma unroll
    for (int i = ty; i < 32; i += 8)
      t[i][tx] = W2[(size_t)(k0 + i) * 1024 + n0 + tx];
    __syncthreads();
#pragma unroll
    for (int i = ty; i < 32; i += 8)
      W2f[frag_off(n0 + i, k0 + tx, 32)] = f_to_bf_raw(t[tx][i]);
    return;
  }

  if (bx < 7680) {                       // WHf [2048 n,1024 k] (KT32=32)
    const int tt = bx - 5632;
    const int k0 = (tt & 31) * 32;
    const int n0 = (tt >> 5) * 32;       // region-uniform per block
#pragma unroll
    for (int i = ty; i < 32; i += 8) {
      const int n = n0 + tx;
      float v;
      if (n0 < 512)
        v = Wc1[(size_t)(k0 + i) * 512 + n];
      else if (n0 < 1024)
        v = Wt1[(size_t)(k0 + i) * 512 + (n - 512)];
      else
        v = Wk1[(size_t)(k0 + i) * 1024 + (n - 1024)]
          + Wk1[(size_t)(k0 + i + 1024) * 1024 + (n - 1024)];
      t[i][tx] = v;
    }
    __syncthreads();
#pragma unroll
    for (int i = ty; i < 32; i += 8)
      WHf[frag_off(n0 + i, k0 + tx, 32)] = f_to_bf_raw(t[tx][i]);
    return;
  }

  {                                      // bias2048 / w2cat
    int n = (bx - 7680) * 256 + tid;
    float b, w;
    if (n < 512)       { b = bc1[n];        w = Wc2[n]; }
    else if (n < 1024) { b = bt1[n - 512];  w = Wt2[n - 512]; }
    else               { b = bk1[n - 1024]; w = Wk2[n - 1024]; }
    bias2048[n] = b;
    w2cat[n] = w;
  }
}

#define GLD_LDS(gp, lp)                                                        \
  __builtin_amdgcn_global_load_lds(                                            \
      (const __attribute__((address_space(1))) void*)(gp),                     \
      (__attribute__((address_space(3))) void*)(lp), 16, 0, 0)

#define SCB __builtin_amdgcn_sched_barrier(0)

#define MFMA_BF16(a, b, c) __builtin_amdgcn_mfma_f32_16x16x32_bf16(a, b, c, 0, 0, 0)

// ===========================================================================
// GEMM core v9 (HW-verified best for gemm1/gemm2): 128x128 tile, BK=64,
// 4 waves, 48KB LDS (~2-3 blk/CU), one __syncthreads per K-step.
// Cross-block overlap (m114) hides the serialized phases at this occupancy.
// ===========================================================================
#define GEMM_CORE_V9(ACC_DECL)                                                 \
  __shared__ __align__(16) unsigned short As[3][128 * 64];  /* 48 KB */        \
  const int tid  = threadIdx.x;                                                \
  const int lane = tid & 63;                                                   \
  const int wave = tid >> 6;                                                   \
  const int m0 = blockIdx.x * 128;                                             \
  const int n0 = blockIdx.y * 128;                                             \
  const int wm = (wave & 1) * 64;                                              \
  const int wn = (wave >> 1) * 64;                                             \
  const int fr = lane & 15;                                                    \
  const int fq = lane >> 4;                                                    \
  ACC_DECL;                                                                    \
  constexpr int KT   = K >> 6;     /* BK=64 iterations      */                 \
  constexpr int KT32 = K >> 5;     /* 32-wide k-tiles (B)   */                 \
  const size_t rowb = (size_t)K * 2;                                           \
  const int srow8  = lane >> 3;                 /* 0..7 row in 8-row group */  \
  const int schunk = (lane & 7) ^ srow8;        /* swizzled global chunk   */  \
  const char* gA = (const char*)A + (size_t)(m0 + wave * 32 + srow8) * rowb    \
                   + schunk * 16;                                              \
  char* lA = (char*)&As[0][0] + wave * 4096 + lane * 16;                       \
  const unsigned short* gB =                                                   \
      Bf + ((size_t)(((n0 + wn) >> 4) * KT32) * 64 + lane) * 8;                \
  const int fsA = (wm + fr) * 128;                                             \
  const int sl0 = ((fq)     ^ (fr & 7)) * 16;                                  \
  const int sl1 = ((4 + fq) ^ (fr & 7)) * 16;                                  \
  short8 FbP[2][2][4];                                                         \
  _Pragma("unroll")                                                            \
  for (int j = 0; j < 4; ++j)                                                  \
    GLD_LDS(gA + (size_t)j * 8 * rowb, lA + j * 1024);                         \
  _Pragma("unroll")                                                            \
  for (int j = 0; j < 4; ++j)                                                  \
    GLD_LDS(gA + 128 + (size_t)j * 8 * rowb,                                   \
            (char*)&As[1][0] + wave * 4096 + lane * 16 + j * 1024);            \
  _Pragma("unroll")                                                            \
  for (int s = 0; s < 2; ++s)                                                  \
    _Pragma("unroll")                                                          \
    for (int ni = 0; ni < 4; ++ni)                                             \
      FbP[0][s][ni] = *(const short8*)(gB + ((size_t)ni * KT32 + s) * 512);    \
  _Pragma("unroll")                                                            \
  for (int k = 0; k < KT; ++k) {       /* constexpr bound -> full unroll */    \
    __syncthreads();   /* drains DMA(k+1) (one full iter in flight) */         \
    if (k + 2 < KT) {                                                          \
      char* d = (char*)&As[(k + 2) % 3][0] + wave * 4096 + lane * 16;          \
      const char* g = gA + (size_t)(k + 2) * 128;                              \
      _Pragma("unroll")                                                        \
      for (int j = 0; j < 4; ++j)                                              \
        GLD_LDS(g + (size_t)j * 8 * rowb, d + j * 1024);                       \
    }                                                                          \
    if (k + 1 < KT) {                                                          \
      _Pragma("unroll")                                                        \
      for (int s = 0; s < 2; ++s)                                              \
        _Pragma("unroll")                                                      \
        for (int ni = 0; ni < 4; ++ni)                                         \
          FbP[(k + 1) & 1][s][ni] = *(const short8*)                           \
              (gB + ((size_t)ni * KT32 + 2 * (k + 1) + s) * 512);              \
    }                                                                          \
    const char* bA = (const char*)&As[k % 3][0];                               \
    short8 Fa0[4], Fa1[4];                                                     \
    _Pragma("unroll")                                                          \
    for (int mi = 0; mi < 4; ++mi)                                             \
      Fa0[mi] = *(const short8*)(bA + fsA + mi * 2048 + sl0);                  \
    _Pragma("unroll")                                                          \
    for (int mi = 0; mi < 4; ++mi)                                             \
      Fa1[mi] = *(const short8*)(bA + fsA + mi * 2048 + sl1);                  \
    _Pragma("unroll")                                                          \
    for (int mi = 0; mi < 4; ++mi)                                             \
      _Pragma("unroll")                                                        \
      for (int ni = 0; ni < 4; ++ni)                                           \
        acc[mi][ni] = __builtin_amdgcn_mfma_f32_16x16x32_bf16(                 \
            Fa0[mi], FbP[k & 1][0][ni], acc[mi][ni], 0, 0, 0);                 \
    _Pragma("unroll")                                                          \
    for (int mi = 0; mi < 4; ++mi)                                             \
      _Pragma("unroll")                                                        \
      for (int ni = 0; ni < 4; ++ni)                                           \
        acc[mi][ni] = __builtin_amdgcn_mfma_f32_16x16x32_bf16(                 \
            Fa1[mi], FbP[k & 1][1][ni], acc[mi][ni], 0, 0, 0);                 \
  }

#define ACC_INIT4                                                              \
  floatx4 acc[4][4];                                                           \
  _Pragma("unroll")                                                            \
  for (int i = 0; i < 4; ++i)                                                  \
    _Pragma("unroll")                                                          \
    for (int j = 0; j < 4; ++j) acc[i][j] = (floatx4){0.f, 0.f, 0.f, 0.f}

// ===========================================================================
// GEMM core v13 (HW-verified best for heads, R7: 68.6us / 1002 TF / 0
// conflicts): 256x256 tile, BK=64, 8 waves, 128KB LDS, 4-phase schedule
// (T3), counted vmcnt once per K-tile (T4), setprio (T5), A-LDS XOR
// swizzle (T2: global chunk (lane&3)^((lane>>3)&3), read fq^((fr>>1)&3)).
// ===========================================================================
#define ST_A(T, kh)                                                            \
  GLD_LDS(gA0 + (size_t)(T) * 128 + (kh) * 64,                                 \
          Lds + ((T) & 1) * 65536 + (kh) * 16384 + lA0);                       \
  GLD_LDS(gA1 + (size_t)(T) * 128 + (kh) * 64,                                 \
          Lds + ((T) & 1) * 65536 + (kh) * 16384 + lA0 + 8192)

#define ST_B(T, kh)                                                            \
  GLD_LDS(gB0 + (size_t)(2 * (T) + (kh)) * 1024,                               \
          Lds + ((T) & 1) * 65536 + (kh) * 16384 + lB0);                       \
  GLD_LDS(gB1 + (size_t)(2 * (T) + (kh)) * 1024,                               \
          Lds + ((T) & 1) * 65536 + (kh) * 16384 + lB0 + 8192)

#define FB4(pb)                                                                \
  Fb[0] = *(const short8*)((pb) + fbB);                                        \
  Fb[1] = *(const short8*)((pb) + fbB + 1024);                                 \
  Fb[2] = *(const short8*)((pb) + fbB + 2048);                                 \
  Fb[3] = *(const short8*)((pb) + fbB + 3072)

#define MFMA16(mh)                                                             \
  acc[(mh)*4+0][0] = MFMA_BF16(Fa0, Fb[0], acc[(mh)*4+0][0]);                  \
  acc[(mh)*4+0][1] = MFMA_BF16(Fa0, Fb[1], acc[(mh)*4+0][1]);                  \
  acc[(mh)*4+0][2] = MFMA_BF16(Fa0, Fb[2], acc[(mh)*4+0][2]);                  \
  acc[(mh)*4+0][3] = MFMA_BF16(Fa0, Fb[3], acc[(mh)*4+0][3]);                  \
  acc[(mh)*4+1][0] = MFMA_BF16(Fa1, Fb[0], acc[(mh)*4+1][0]);                  \
  acc[(mh)*4+1][1] = MFMA_BF16(Fa1, Fb[1], acc[(mh)*4+1][1]);                  \
  acc[(mh)*4+1][2] = MFMA_BF16(Fa1, Fb[2], acc[(mh)*4+1][2]);                  \
  acc[(mh)*4+1][3] = MFMA_BF16(Fa1, Fb[3], acc[(mh)*4+1][3]);                  \
  acc[(mh)*4+2][0] = MFMA_BF16(Fa2, Fb[0], acc[(mh)*4+2][0]);                  \
  acc[(mh)*4+2][1] = MFMA_BF16(Fa2, Fb[1], acc[(mh)*4+2][1]);                  \
  acc[(mh)*4+2][2] = MFMA_BF16(Fa2, Fb[2], acc[(mh)*4+2][2]);                  \
  acc[(mh)*4+2][3] = MFMA_BF16(Fa2, Fb[3], acc[(mh)*4+2][3]);                  \
  acc[(mh)*4+3][0] = MFMA_BF16(Fa3, Fb[0], acc[(mh)*4+3][0]);                  \
  acc[(mh)*4+3][1] = MFMA_BF16(Fa3, Fb[1], acc[(mh)*4+3][1]);                  \
  acc[(mh)*4+3][2] = MFMA_BF16(Fa3, Fb[2], acc[(mh)*4+3][2]);                  \
  acc[(mh)*4+3][3] = MFMA_BF16(Fa3, Fb[3], acc[(mh)*4+3][3])

#define PHASE(TT, ks, mh, EXTRA_READS, STAGE_STMT, PRE_BAR2)                   \
  {                                                                            \
    const char* pb = Lds + ((TT) & 1) * 65536 + (ks) * 16384;                  \
    short8 Fa0 = *(const short8*)(pb + faB + ((mh)*4+0)*1024);                 \
    short8 Fa1 = *(const short8*)(pb + faB + ((mh)*4+1)*1024);                 \
    short8 Fa2 = *(const short8*)(pb + faB + ((mh)*4+2)*1024);                 \
    short8 Fa3 = *(const short8*)(pb + faB + ((mh)*4+3)*1024);                 \
    EXTRA_READS;                                                               \
    STAGE_STMT;                                                                \
    SCB; __builtin_amdgcn_s_barrier(); SCB;                                    \
    __builtin_amdgcn_s_setprio(1);                                             \
    MFMA16(mh);                                                                \
    __builtin_amdgcn_s_setprio(0);                                             \
    PRE_BAR2;                                                                  \
    SCB; __builtin_amdgcn_s_barrier(); SCB;                                    \
  }

#define GEMM_CORE_V13(ACC_DECL)                                                \
  __shared__ __align__(16) char Lds[131072];                                   \
  const int tid  = threadIdx.x;                                                \
  const int lane = tid & 63;                                                   \
  const int wave = tid >> 6;           /* 0..7 */                              \
  const int m0 = blockIdx.x * 256;                                             \
  const int n0 = blockIdx.y * 256;                                             \
  const int wm = (wave & 1) * 128;     /* 2 M-waves x 4 N-waves */             \
  const int wn = (wave >> 1) * 64;                                             \
  const int fr = lane & 15;                                                    \
  const int fq = lane >> 4;                                                    \
  ACC_DECL;                                                                    \
  constexpr int KT   = K >> 6;                                                 \
  constexpr int KT32 = K >> 5;                                                 \
  const size_t rowb = (size_t)K * 2;                                           \
  const char* gA0 = (const char*)A                                             \
      + (size_t)(m0 + wave * 16 + (lane >> 2)) * rowb                          \
      + (((lane & 3) ^ ((lane >> 3) & 3)) * 16);                               \
  const char* gA1 = gA0 + (size_t)128 * rowb;                                  \
  const char* gB0 = (const char*)Bf                                            \
      + ((size_t)((n0 >> 4) + wave) * KT32) * 1024 + lane * 16;                \
  const char* gB1 = gB0 + (size_t)8 * KT32 * 1024;                             \
  const int lA0 = wave * 1024 + lane * 16;                                     \
  const int lB0 = 32768 + wave * 1024 + lane * 16;                             \
  const int faB = (wm + fr) * 64 + ((fq ^ ((fr >> 1) & 3)) * 16);              \
  const int fbB = 32768 + ((wave >> 1) * 4) * 1024 + lane * 16;                \
  short8 Fb[4];                                                                \
  /* prologue: T0 full (8 DMAs) + T1 kh0 (4 DMAs); order pinned */             \
  ST_A(0, 0); ST_B(0, 0); ST_A(0, 1); ST_B(0, 1);                              \
  SCB;                                                                         \
  ST_A(1, 0); ST_B(1, 0);                                                      \
  SCB;                                                                         \
  asm volatile("s_waitcnt vmcnt(4)" ::: "memory");  /* T0 landed (mine) */     \
  __builtin_amdgcn_s_barrier();        /* -> T0 landed (all waves) */          \
  SCB;                                                                         \
  _Pragma("unroll")                                                            \
  for (int T = 0; T < KT; ++T) {       /* constexpr bound -> full unroll */    \
    PHASE(T, 0, 0, FB4(pb), if (T + 1 < KT) { ST_A(T + 1, 1); }, (void)0);     \
    PHASE(T, 0, 1, (void)0, if (T + 1 < KT) { ST_B(T + 1, 1); }, (void)0);     \
    PHASE(T, 1, 0, FB4(pb), if (T + 2 < KT) { ST_A(T + 2, 0); }, (void)0);     \
    PHASE(T, 1, 1, (void)0, if (T + 2 < KT) { ST_B(T + 2, 0); },               \
          if (T + 1 < KT) {                                                    \
            SCB;                                                               \
            if (T + 2 < KT) {                                                  \
              asm volatile("s_waitcnt vmcnt(4)" ::: "memory");                 \
            } else {                                                           \
              asm volatile("s_waitcnt vmcnt(0)" ::: "memory");                 \
            }                                                                  \
            SCB;                                                               \
          });                                                                  \
  }

#define ACC_INIT8                                                              \
  floatx4 acc[8][4];                                                           \
  _Pragma("unroll")                                                            \
  for (int i = 0; i < 8; ++i)                                                  \
    _Pragma("unroll")                                                          \
    for (int j = 0; j < 4; ++j) acc[i][j] = (floatx4){0.f, 0.f, 0.f, 0.f}

// ---------------------------------------------------------------------------
// GEMM: C = relu(A @ B^T + bias), bf16 out (row-major). v9 core (verified).
// ---------------------------------------------------------------------------
template <int K>
__global__ __launch_bounds__(256, 2) void gemm_bias_relu(
    const unsigned short* __restrict__ A,
    const unsigned short* __restrict__ Bf,
    const float* __restrict__ bias,
    unsigned short* __restrict__ C,
    int M, int N) {
  GEMM_CORE_V9(ACC_INIT4)

  // Epilogue: C/D layout col=lane&15, row=(lane>>4)*4+reg
#pragma unroll
  for (int ni = 0; ni < 4; ++ni) {
    const int gn = n0 + wn + ni * 16 + fr;
    const float bv = bias[gn];
#pragma unroll
    for (int mi = 0; mi < 4; ++mi) {
#pragma unroll
      for (int r = 0; r < 4; ++r) {
        const int gm = m0 + wm + mi * 16 + fq * 4 + r;
        float v = acc[mi][ni][r] + bv;
        v = v > 0.f ? v : 0.f;
        C[(size_t)gm * N + gn] = f_to_bf_raw(v);
      }
    }
  }
}

// ---------------------------------------------------------------------------
// Fused heads GEMM: relu(G @ WH^T + bias2048) dotted with w2cat in-register,
// non-atomic partials part[j][row], j = blockIdx.y*4 + (wave>>1) in [0,32).
// v13 core (verified best: 68.6us, 0 conflicts). Epilogue verified.
// ---------------------------------------------------------------------------
template <int K>
__global__ __launch_bounds__(512, 2) void gemm_heads_fused(
    const unsigned short* __restrict__ A,    // G row-major [B,1024]
    const unsigned short* __restrict__ Bf,   // WHf frag-major [2048,1024]
    const float* __restrict__ bias,          // bias2048
    const float* __restrict__ w2,            // w2cat
    float* __restrict__ part,                // [32][B_ROWS] (maybe row-offset)
    int M, int N) {
  GEMM_CORE_V13(ACC_INIT8)

  const int j = blockIdx.y * 4 + (wave >> 1);
  float w2v[4], bv[4];
#pragma unroll
  for (int ni = 0; ni < 4; ++ni) {
    const int gn = n0 + wn + ni * 16 + fr;
    w2v[ni] = w2[gn];
    bv[ni]  = bias[gn];
  }
#pragma unroll
  for (int mi = 0; mi < 8; ++mi) {
#pragma unroll
    for (int r = 0; r < 4; ++r) {
      float p = 0.f;
#pragma unroll
      for (int ni = 0; ni < 4; ++ni) {
        float v = acc[mi][ni][r] + bv[ni];
        v = v > 0.f ? v : 0.f;
        p += v * w2v[ni];
      }
      p += __shfl_xor(p, 1);
      p += __shfl_xor(p, 2);
      p += __shfl_xor(p, 4);
      p += __shfl_xor(p, 8);
      if (fr == 0) {
        const int gm = m0 + wm + mi * 16 + fq * 4 + r;
        part[(size_t)j * B_ROWS + gm] = p;
      }
    }
  }
}

// ---------------------------------------------------------------------------
// Final: sum partials, sigmoid, broadcast to out [3, B, 9]. 1 thread/row.
// ---------------------------------------------------------------------------
__global__ __launch_bounds__(256) void final_out(
    const float* __restrict__ part,
    const float* __restrict__ bc2, const float* __restrict__ bt2,
    const float* __restrict__ bk2, float* __restrict__ out) {
  const int row = blockIdx.x * 256 + threadIdx.x;
  float sc = 0.f, st = 0.f, sk = 0.f;
#pragma unroll
  for (int j = 0; j < 8; ++j)  sc += part[(size_t)j * B_ROWS + row];
#pragma unroll
  for (int j = 8; j < 16; ++j) st += part[(size_t)j * B_ROWS + row];
#pragma unroll
  for (int j = 16; j < 32; ++j) sk += part[(size_t)j * B_ROWS + row];
  const float cv = 1.f / (1.f + expf(-(sc + bc2[0])));
  const float tv = 1.f / (1.f + expf(-(st + bt2[0])));
  const float kv = 1.f / (1.f + expf(-(sk + bk2[0])));
  float* o0 = out + (size_t)row * N_AG;
  float* o1 = out + (size_t)(B_ROWS + row) * N_AG;
  float* o2 = out + (size_t)(2 * B_ROWS + row) * N_AG;
#pragma unroll
  for (int a = 0; a < N_AG; ++a) { o0[a] = cv; o1[a] = tv; o2[a] = kv; }
}

// ---------------------------------------------------------------------------
// Workspace plan (round-0 verified):
// FULL path (needs 70 MB + 16 KB):
//   [0,32MB)  slotA: obs_bf(16MB) + W1f(1MB @16MB)  --gemm2--> G(32MB)
//   [32,64MB) slotB: G1(32MB)                       --heads--> PART(2MB)
//   [64,66MB) W2f   [66,70MB) WHf   [70MB,+8KB) bias2048  [+8KB,+16KB) w2cat
// SPLIT path (ws_size < FULL_NEED; needs 57 MB + 16 KB): two 8192-row halves.
// ---------------------------------------------------------------------------
extern "C" void kernel_launch(void* const* d_in, const int* in_sizes, int n_in,
                              void* d_out, int out_size, void* d_ws, size_t ws_size,
                              hipStream_t stream) {
  const float* obs = (const float*)d_in[0];
  // d_in[1] agent_positions: unused (outputs don't depend on it)
  const float* W1  = (const float*)d_in[2];
  const float* b1  = (const float*)d_in[3];
  const float* W2  = (const float*)d_in[4];
  const float* b2  = (const float*)d_in[5];
  const float* Wc1 = (const float*)d_in[6];
  const float* bc1 = (const float*)d_in[7];
  const float* Wc2 = (const float*)d_in[8];
  const float* bc2 = (const float*)d_in[9];
  const float* Wt1 = (const float*)d_in[10];
  const float* bt1 = (const float*)d_in[11];
  const float* Wt2 = (const float*)d_in[12];
  const float* bt2 = (const float*)d_in[13];
  const float* Wk1 = (const float*)d_in[14];
  const float* bk1 = (const float*)d_in[15];
  const float* Wk2 = (const float*)d_in[16];
  const float* bk2 = (const float*)d_in[17];
  float* out = (float*)d_out;

  char* ws = (char*)d_ws;
  const size_t MB = 1024 * 1024;
  const size_t FULL_NEED = 70 * MB + 16 * 1024;

  unsigned short *obs_bf, *W1f, *W2f, *WHf, *G1, *G;
  float *bias2048, *w2cat, *PART;
  const bool full = (ws_size == 0) || (ws_size >= FULL_NEED);

  if (full) {
    obs_bf   = (unsigned short*)(ws + 0);
    W1f      = (unsigned short*)(ws + 16 * MB);
    G        = (unsigned short*)(ws + 0);        // alias: obs_bf+W1f dead
    G1       = (unsigned short*)(ws + 32 * MB);
    PART     = (float*)(ws + 32 * MB);           // alias: G1 dead
    W2f      = (unsigned short*)(ws + 64 * MB);
    WHf      = (unsigned short*)(ws + 66 * MB);
    bias2048 = (float*)(ws + 70 * MB);
    w2cat    = (float*)(ws + 70 * MB + 8 * 1024);
  } else {
    obs_bf   = (unsigned short*)(ws + 0);        // 16 MB, full B
    G1       = (unsigned short*)(ws + 16 * MB);  // 16 MB (half)
    G        = (unsigned short*)(ws + 32 * MB);  // 16 MB (half)
    W1f      = (unsigned short*)(ws + 48 * MB);
    W2f      = (unsigned short*)(ws + 49 * MB);
    WHf      = (unsigned short*)(ws + 51 * MB);
    bias2048 = (float*)(ws + 55 * MB);
    w2cat    = (float*)(ws + 55 * MB + 8 * 1024);
    PART     = (float*)(ws + 55 * MB + 16 * 1024); // 2 MB, full B
  }

  prep_all<<<7688, 256, 0, stream>>>(obs, W1, W2, Wc1, Wt1, Wk1,
                                     bc1, bt1, bk1, Wc2, Wt2, Wk2,
                                     obs_bf, W1f, W2f, WHf, bias2048, w2cat);

  if (full) {
    gemm_bias_relu<512><<<dim3(128, 8), 256, 0, stream>>>(
        obs_bf, W1f, b1, G1, B_ROWS, 1024);
    gemm_bias_relu<1024><<<dim3(128, 8), 256, 0, stream>>>(
        G1, W2f, b2, G, B_ROWS, 1024);
    gemm_heads_fused<1024><<<dim3(64, 8), 512, 0, stream>>>(
        G, WHf, bias2048, w2cat, PART, B_ROWS, 2048);
  } else {
    for (int h = 0; h < 2; ++h) {
      const size_t ro = (size_t)h * 8192;
      gemm_bias_relu<512><<<dim3(64, 8), 256, 0, stream>>>(
          obs_bf + ro * 512, W1f, b1, G1, 8192, 1024);
      gemm_bias_relu<1024><<<dim3(64, 8), 256, 0, stream>>>(
          G1, W2f, b2, G, 8192, 1024);
      gemm_heads_fused<1024><<<dim3(32, 8), 512, 0, stream>>>(
          G, WHf, bias2048, w2cat, PART + ro, 8192, 2048);
    }
  }

  final_out<<<B_ROWS / 256, 256, 0, stream>>>(PART, bc2, bt2, bk2, out);
}

// Round 13
// 246.143 us; speedup vs baseline: 1.0073x; 1.0073x over previous
//
#include <hip/hip_runtime.h>
#include <hip/hip_bf16.h>

// Problem constants
#define B_ROWS 16384
#define OBS_D  512
#define H_D    1024
#define N_AG   9

typedef __attribute__((ext_vector_type(8))) short short8;
typedef __attribute__((ext_vector_type(4))) float floatx4;

__device__ __forceinline__ unsigned short f_to_bf_raw(float f) {
  union { float f; unsigned u; } c; c.f = f;
  unsigned u = c.u;
  u = u + 0x7FFF + ((u >> 16) & 1);   // round-to-nearest-even
  return (unsigned short)(u >> 16);
}

// Fragment-major WEIGHT layout (B operand only; A stays row-major):
//   frag_tile = (n>>4)*KT32 + (k>>5)
//   lane      = (n&15) | (((k>>3)&3)<<4)
//   j         = k&7
// offset (bf16 units) = (frag_tile*64 + lane)*8 + j
__device__ __forceinline__ size_t frag_off(int n, int k, int KT32) {
  const int ft = (n >> 4) * KT32 + (k >> 5);
  const int ln = (n & 15) | (((k >> 3) & 3) << 4);
  return ((size_t)ft * 64 + ln) * 8 + (k & 7);
}

// ---------------------------------------------------------------------------
// Mega-prep (proven, unchanged)
// ---------------------------------------------------------------------------
__global__ __launch_bounds__(256) void prep_all(
    const float* __restrict__ obs,
    const float* __restrict__ W1, const float* __restrict__ W2,
    const float* __restrict__ Wc1, const float* __restrict__ Wt1,
    const float* __restrict__ Wk1,
    const float* __restrict__ bc1, const float* __restrict__ bt1,
    const float* __restrict__ bk1,
    const float* __restrict__ Wc2, const float* __restrict__ Wt2,
    const float* __restrict__ Wk2,
    unsigned short* __restrict__ obs_bf,
    unsigned short* __restrict__ W1f, unsigned short* __restrict__ W2f,
    unsigned short* __restrict__ WHf,
    float* __restrict__ bias2048, float* __restrict__ w2cat) {
  __shared__ float t[32][33];
  const int bx  = blockIdx.x;
  const int tid = threadIdx.x;

  if (bx < 4096) {                       // obs fp32 -> bf16, 8 elems/thread
    int i = (bx * 256 + tid) * 8;
    float4 a = *(const float4*)(obs + i);
    float4 b = *(const float4*)(obs + i + 4);
    short8 o;
    o[0] = (short)f_to_bf_raw(a.x); o[1] = (short)f_to_bf_raw(a.y);
    o[2] = (short)f_to_bf_raw(a.z); o[3] = (short)f_to_bf_raw(a.w);
    o[4] = (short)f_to_bf_raw(b.x); o[5] = (short)f_to_bf_raw(b.y);
    o[6] = (short)f_to_bf_raw(b.z); o[7] = (short)f_to_bf_raw(b.w);
    *(short8*)(obs_bf + i) = o;
    return;
  }

  const int tx = tid & 31;
  const int ty = tid >> 5;   // 0..7

  if (bx < 4608) {                       // W1 [512,1024] -> W1f (K=512,KT32=16)
    const int tt = bx - 4096;
    const int k0 = (tt & 15) * 32;
    const int n0 = (tt >> 4) * 32;
#pragma unroll
    for (int i = ty; i < 32; i += 8)
      t[i][tx] = W1[(size_t)(k0 + i) * 1024 + n0 + tx];
    __syncthreads();
#pragma unroll
    for (int i = ty; i < 32; i += 8)
      W1f[frag_off(n0 + i, k0 + tx, 16)] = f_to_bf_raw(t[tx][i]);
    return;
  }

  if (bx < 5632) {                       // W2 [1024,1024] -> W2f (KT32=32)
    const int tt = bx - 4608;
    const int k0 = (tt & 31) * 32;
    const int n0 = (tt >> 5) * 32;
#pragma unroll
    for (int i = ty; i < 32; i += 8)
      t[i][tx] = W2[(size_t)(k0 + i) * 1024 + n0 + tx];
    __syncthreads();
#pragma unroll
    for (int i = ty; i < 32; i += 8)
      W2f[frag_off(n0 + i, k0 + tx, 32)] = f_to_bf_raw(t[tx][i]);
    return;
  }

  if (bx < 7680) {                       // WHf [2048 n,1024 k] (KT32=32)
    const int tt = bx - 5632;
    const int k0 = (tt & 31) * 32;
    const int n0 = (tt >> 5) * 32;       // region-uniform per block
#pragma unroll
    for (int i = ty; i < 32; i += 8) {
      const int n = n0 + tx;
      float v;
      if (n0 < 512)
        v = Wc1[(size_t)(k0 + i) * 512 + n];
      else if (n0 < 1024)
        v = Wt1[(size_t)(k0 + i) * 512 + (n - 512)];
      else
        v = Wk1[(size_t)(k0 + i) * 1024 + (n - 1024)]
          + Wk1[(size_t)(k0 + i + 1024) * 1024 + (n - 1024)];
      t[i][tx] = v;
    }
    __syncthreads();
#pragma unroll
    for (int i = ty; i < 32; i += 8)
      WHf[frag_off(n0 + i, k0 + tx, 32)] = f_to_bf_raw(t[tx][i]);
    return;
  }

  {                                      // bias2048 / w2cat
    int n = (bx - 7680) * 256 + tid;
    float b, w;
    if (n < 512)       { b = bc1[n];        w = Wc2[n]; }
    else if (n < 1024) { b = bt1[n - 512];  w = Wt2[n - 512]; }
    else               { b = bk1[n - 1024]; w = Wk2[n - 1024]; }
    bias2048[n] = b;
    w2cat[n] = w;
  }
}

#define GLD_LDS(gp, lp)                                                        \
  __builtin_amdgcn_global_load_lds(                                            \
      (const __attribute__((address_space(1))) void*)(gp),                     \
      (__attribute__((address_space(3))) void*)(lp), 16, 0, 0)

#define SCB __builtin_amdgcn_sched_barrier(0)

#define MFMA_BF16(a, b, c) __builtin_amdgcn_mfma_f32_16x16x32_bf16(a, b, c, 0, 0, 0)

// ===========================================================================
// GEMM core v9 (HW-verified best for K=512 / gemm1): 128x128 tile, BK=64,
// 4 waves, 48KB LDS (~2-3 blk/CU), one __syncthreads per K-step.
// Cross-block overlap (m114) hides the serialized phases at this occupancy.
// ===========================================================================
#define GEMM_CORE_V9(ACC_DECL)                                                 \
  __shared__ __align__(16) unsigned short As[3][128 * 64];  /* 48 KB */        \
  const int tid  = threadIdx.x;                                                \
  const int lane = tid & 63;                                                   \
  const int wave = tid >> 6;                                                   \
  const int m0 = blockIdx.x * 128;                                             \
  const int n0 = blockIdx.y * 128;                                             \
  const int wm = (wave & 1) * 64;                                              \
  const int wn = (wave >> 1) * 64;                                             \
  const int fr = lane & 15;                                                    \
  const int fq = lane >> 4;                                                    \
  ACC_DECL;                                                                    \
  constexpr int KT   = K >> 6;     /* BK=64 iterations      */                 \
  constexpr int KT32 = K >> 5;     /* 32-wide k-tiles (B)   */                 \
  const size_t rowb = (size_t)K * 2;                                           \
  const int srow8  = lane >> 3;                 /* 0..7 row in 8-row group */  \
  const int schunk = (lane & 7) ^ srow8;        /* swizzled global chunk   */  \
  const char* gA = (const char*)A + (size_t)(m0 + wave * 32 + srow8) * rowb    \
                   + schunk * 16;                                              \
  char* lA = (char*)&As[0][0] + wave * 4096 + lane * 16;                       \
  const unsigned short* gB =                                                   \
      Bf + ((size_t)(((n0 + wn) >> 4) * KT32) * 64 + lane) * 8;                \
  const int fsA = (wm + fr) * 128;                                             \
  const int sl0 = ((fq)     ^ (fr & 7)) * 16;                                  \
  const int sl1 = ((4 + fq) ^ (fr & 7)) * 16;                                  \
  short8 FbP[2][2][4];                                                         \
  _Pragma("unroll")                                                            \
  for (int j = 0; j < 4; ++j)                                                  \
    GLD_LDS(gA + (size_t)j * 8 * rowb, lA + j * 1024);                         \
  _Pragma("unroll")                                                            \
  for (int j = 0; j < 4; ++j)                                                  \
    GLD_LDS(gA + 128 + (size_t)j * 8 * rowb,                                   \
            (char*)&As[1][0] + wave * 4096 + lane * 16 + j * 1024);            \
  _Pragma("unroll")                                                            \
  for (int s = 0; s < 2; ++s)                                                  \
    _Pragma("unroll")                                                          \
    for (int ni = 0; ni < 4; ++ni)                                             \
      FbP[0][s][ni] = *(const short8*)(gB + ((size_t)ni * KT32 + s) * 512);    \
  _Pragma("unroll")                                                            \
  for (int k = 0; k < KT; ++k) {       /* constexpr bound -> full unroll */    \
    __syncthreads();   /* drains DMA(k+1) (one full iter in flight) */         \
    if (k + 2 < KT) {                                                          \
      char* d = (char*)&As[(k + 2) % 3][0] + wave * 4096 + lane * 16;          \
      const char* g = gA + (size_t)(k + 2) * 128;                              \
      _Pragma("unroll")                                                        \
      for (int j = 0; j < 4; ++j)                                              \
        GLD_LDS(g + (size_t)j * 8 * rowb, d + j * 1024);                       \
    }                                                                          \
    if (k + 1 < KT) {                                                          \
      _Pragma("unroll")                                                        \
      for (int s = 0; s < 2; ++s)                                              \
        _Pragma("unroll")                                                      \
        for (int ni = 0; ni < 4; ++ni)                                         \
          FbP[(k + 1) & 1][s][ni] = *(const short8*)                           \
              (gB + ((size_t)ni * KT32 + 2 * (k + 1) + s) * 512);              \
    }                                                                          \
    const char* bA = (const char*)&As[k % 3][0];                               \
    short8 Fa0[4], Fa1[4];                                                     \
    _Pragma("unroll")                                                          \
    for (int mi = 0; mi < 4; ++mi)                                             \
      Fa0[mi] = *(const short8*)(bA + fsA + mi * 2048 + sl0);                  \
    _Pragma("unroll")                                                          \
    for (int mi = 0; mi < 4; ++mi)                                             \
      Fa1[mi] = *(const short8*)(bA + fsA + mi * 2048 + sl1);                  \
    _Pragma("unroll")                                                          \
    for (int mi = 0; mi < 4; ++mi)                                             \
      _Pragma("unroll")                                                        \
      for (int ni = 0; ni < 4; ++ni)                                           \
        acc[mi][ni] = __builtin_amdgcn_mfma_f32_16x16x32_bf16(                 \
            Fa0[mi], FbP[k & 1][0][ni], acc[mi][ni], 0, 0, 0);                 \
    _Pragma("unroll")                                                          \
    for (int mi = 0; mi < 4; ++mi)                                             \
      _Pragma("unroll")                                                        \
      for (int ni = 0; ni < 4; ++ni)                                           \
        acc[mi][ni] = __builtin_amdgcn_mfma_f32_16x16x32_bf16(                 \
            Fa1[mi], FbP[k & 1][1][ni], acc[mi][ni], 0, 0, 0);                 \
  }

#define ACC_INIT4                                                              \
  floatx4 acc[4][4];                                                           \
  _Pragma("unroll")                                                            \
  for (int i = 0; i < 4; ++i)                                                  \
    _Pragma("unroll")                                                          \
    for (int j = 0; j < 4; ++j) acc[i][j] = (floatx4){0.f, 0.f, 0.f, 0.f}

// ===========================================================================
// GEMM core v13 (HW-verified, R7/R12: heads 68.6-70.5us / ~1000 TF / 0
// conflicts): 256x256 tile, BK=64, 8 waves, 128KB LDS, 4-phase schedule
// (T3), counted vmcnt once per K-tile (T4), setprio (T5), A-LDS XOR
// swizzle (T2: global chunk (lane&3)^((lane>>3)&3), read fq^((fr>>1)&3)).
// Round-12: also applied to gemm2 (K=1024, same K-regime as heads; grid
// 64x4 = 256 blocks = 1/CU single round).
// ===========================================================================
#define ST_A(T, kh)                                                            \
  GLD_LDS(gA0 + (size_t)(T) * 128 + (kh) * 64,                                 \
          Lds + ((T) & 1) * 65536 + (kh) * 16384 + lA0);                       \
  GLD_LDS(gA1 + (size_t)(T) * 128 + (kh) * 64,                                 \
          Lds + ((T) & 1) * 65536 + (kh) * 16384 + lA0 + 8192)

#define ST_B(T, kh)                                                            \
  GLD_LDS(gB0 + (size_t)(2 * (T) + (kh)) * 1024,                               \
          Lds + ((T) & 1) * 65536 + (kh) * 16384 + lB0);                       \
  GLD_LDS(gB1 + (size_t)(2 * (T) + (kh)) * 1024,                               \
          Lds + ((T) & 1) * 65536 + (kh) * 16384 + lB0 + 8192)

#define FB4(pb)                                                                \
  Fb[0] = *(const short8*)((pb) + fbB);                                        \
  Fb[1] = *(const short8*)((pb) + fbB + 1024);                                 \
  Fb[2] = *(const short8*)((pb) + fbB + 2048);                                 \
  Fb[3] = *(const short8*)((pb) + fbB + 3072)

#define MFMA16(mh)                                                             \
  acc[(mh)*4+0][0] = MFMA_BF16(Fa0, Fb[0], acc[(mh)*4+0][0]);                  \
  acc[(mh)*4+0][1] = MFMA_BF16(Fa0, Fb[1], acc[(mh)*4+0][1]);                  \
  acc[(mh)*4+0][2] = MFMA_BF16(Fa0, Fb[2], acc[(mh)*4+0][2]);                  \
  acc[(mh)*4+0][3] = MFMA_BF16(Fa0, Fb[3], acc[(mh)*4+0][3]);                  \
  acc[(mh)*4+1][0] = MFMA_BF16(Fa1, Fb[0], acc[(mh)*4+1][0]);                  \
  acc[(mh)*4+1][1] = MFMA_BF16(Fa1, Fb[1], acc[(mh)*4+1][1]);                  \
  acc[(mh)*4+1][2] = MFMA_BF16(Fa1, Fb[2], acc[(mh)*4+1][2]);                  \
  acc[(mh)*4+1][3] = MFMA_BF16(Fa1, Fb[3], acc[(mh)*4+1][3]);                  \
  acc[(mh)*4+2][0] = MFMA_BF16(Fa2, Fb[0], acc[(mh)*4+2][0]);                  \
  acc[(mh)*4+2][1] = MFMA_BF16(Fa2, Fb[1], acc[(mh)*4+2][1]);                  \
  acc[(mh)*4+2][2] = MFMA_BF16(Fa2, Fb[2], acc[(mh)*4+2][2]);                  \
  acc[(mh)*4+2][3] = MFMA_BF16(Fa2, Fb[3], acc[(mh)*4+2][3]);                  \
  acc[(mh)*4+3][0] = MFMA_BF16(Fa3, Fb[0], acc[(mh)*4+3][0]);                  \
  acc[(mh)*4+3][1] = MFMA_BF16(Fa3, Fb[1], acc[(mh)*4+3][1]);                  \
  acc[(mh)*4+3][2] = MFMA_BF16(Fa3, Fb[2], acc[(mh)*4+3][2]);                  \
  acc[(mh)*4+3][3] = MFMA_BF16(Fa3, Fb[3], acc[(mh)*4+3][3])

#define PHASE(TT, ks, mh, EXTRA_READS, STAGE_STMT, PRE_BAR2)                   \
  {                                                                            \
    const char* pb = Lds + ((TT) & 1) * 65536 + (ks) * 16384;                  \
    short8 Fa0 = *(const short8*)(pb + faB + ((mh)*4+0)*1024);                 \
    short8 Fa1 = *(const short8*)(pb + faB + ((mh)*4+1)*1024);                 \
    short8 Fa2 = *(const short8*)(pb + faB + ((mh)*4+2)*1024);                 \
    short8 Fa3 = *(const short8*)(pb + faB + ((mh)*4+3)*1024);                 \
    EXTRA_READS;                                                               \
    STAGE_STMT;                                                                \
    SCB; __builtin_amdgcn_s_barrier(); SCB;                                    \
    __builtin_amdgcn_s_setprio(1);                                             \
    MFMA16(mh);                                                                \
    __builtin_amdgcn_s_setprio(0);                                             \
    PRE_BAR2;                                                                  \
    SCB; __builtin_amdgcn_s_barrier(); SCB;                                    \
  }

#define GEMM_CORE_V13(ACC_DECL)                                                \
  __shared__ __align__(16) char Lds[131072];                                   \
  const int tid  = threadIdx.x;                                                \
  const int lane = tid & 63;                                                   \
  const int wave = tid >> 6;           /* 0..7 */                              \
  const int m0 = blockIdx.x * 256;                                             \
  const int n0 = blockIdx.y * 256;                                             \
  const int wm = (wave & 1) * 128;     /* 2 M-waves x 4 N-waves */             \
  const int wn = (wave >> 1) * 64;                                             \
  const int fr = lane & 15;                                                    \
  const int fq = lane >> 4;                                                    \
  ACC_DECL;                                                                    \
  constexpr int KT   = K >> 6;                                                 \
  constexpr int KT32 = K >> 5;                                                 \
  const size_t rowb = (size_t)K * 2;                                           \
  const char* gA0 = (const char*)A                                             \
      + (size_t)(m0 + wave * 16 + (lane >> 2)) * rowb                          \
      + (((lane & 3) ^ ((lane >> 3) & 3)) * 16);                               \
  const char* gA1 = gA0 + (size_t)128 * rowb;                                  \
  const char* gB0 = (const char*)Bf                                            \
      + ((size_t)((n0 >> 4) + wave) * KT32) * 1024 + lane * 16;                \
  const char* gB1 = gB0 + (size_t)8 * KT32 * 1024;                             \
  const int lA0 = wave * 1024 + lane * 16;                                     \
  const int lB0 = 32768 + wave * 1024 + lane * 16;                             \
  const int faB = (wm + fr) * 64 + ((fq ^ ((fr >> 1) & 3)) * 16);              \
  const int fbB = 32768 + ((wave >> 1) * 4) * 1024 + lane * 16;                \
  short8 Fb[4];                                                                \
  /* prologue: T0 full (8 DMAs) + T1 kh0 (4 DMAs); order pinned */             \
  ST_A(0, 0); ST_B(0, 0); ST_A(0, 1); ST_B(0, 1);                              \
  SCB;                                                                         \
  ST_A(1, 0); ST_B(1, 0);                                                      \
  SCB;                                                                         \
  asm volatile("s_waitcnt vmcnt(4)" ::: "memory");  /* T0 landed (mine) */     \
  __builtin_amdgcn_s_barrier();        /* -> T0 landed (all waves) */          \
  SCB;                                                                         \
  _Pragma("unroll")                                                            \
  for (int T = 0; T < KT; ++T) {       /* constexpr bound -> full unroll */    \
    PHASE(T, 0, 0, FB4(pb), if (T + 1 < KT) { ST_A(T + 1, 1); }, (void)0);     \
    PHASE(T, 0, 1, (void)0, if (T + 1 < KT) { ST_B(T + 1, 1); }, (void)0);     \
    PHASE(T, 1, 0, FB4(pb), if (T + 2 < KT) { ST_A(T + 2, 0); }, (void)0);     \
    PHASE(T, 1, 1, (void)0, if (T + 2 < KT) { ST_B(T + 2, 0); },               \
          if (T + 1 < KT) {                                                    \
            SCB;                                                               \
            if (T + 2 < KT) {                                                  \
              asm volatile("s_waitcnt vmcnt(4)" ::: "memory");                 \
            } else {                                                           \
              asm volatile("s_waitcnt vmcnt(0)" ::: "memory");                 \
            }                                                                  \
            SCB;                                                               \
          });                                                                  \
  }

#define ACC_INIT8                                                              \
  floatx4 acc[8][4];                                                           \
  _Pragma("unroll")                                                            \
  for (int i = 0; i < 8; ++i)                                                  \
    _Pragma("unroll")                                                          \
    for (int j = 0; j < 4; ++j) acc[i][j] = (floatx4){0.f, 0.f, 0.f, 0.f}

// ---------------------------------------------------------------------------
// GEMM (v9 core): C = relu(A @ B^T + bias), bf16 out. Used for K=512 (gemm1).
// ---------------------------------------------------------------------------
template <int K>
__global__ __launch_bounds__(256, 2) void gemm_bias_relu(
    const unsigned short* __restrict__ A,
    const unsigned short* __restrict__ Bf,
    const float* __restrict__ bias,
    unsigned short* __restrict__ C,
    int M, int N) {
  GEMM_CORE_V9(ACC_INIT4)

  // Epilogue: C/D layout col=lane&15, row=(lane>>4)*4+reg
#pragma unroll
  for (int ni = 0; ni < 4; ++ni) {
    const int gn = n0 + wn + ni * 16 + fr;
    const float bv = bias[gn];
#pragma unroll
    for (int mi = 0; mi < 4; ++mi) {
#pragma unroll
      for (int r = 0; r < 4; ++r) {
        const int gm = m0 + wm + mi * 16 + fq * 4 + r;
        float v = acc[mi][ni][r] + bv;
        v = v > 0.f ? v : 0.f;
        C[(size_t)gm * N + gn] = f_to_bf_raw(v);
      }
    }
  }
}

// ---------------------------------------------------------------------------
// GEMM (v13 core): C = relu(A @ B^T + bias), bf16 out. Used for K=1024
// (gemm2, grid 64x4). Same verified core as heads; epilogue mirrors the
// verified heads indexing (mi 0..8).
// ---------------------------------------------------------------------------
template <int K>
__global__ __launch_bounds__(512, 2) void gemm_bias_relu_v13(
    const unsigned short* __restrict__ A,
    const unsigned short* __restrict__ Bf,
    const float* __restrict__ bias,
    unsigned short* __restrict__ C,
    int M, int N) {
  GEMM_CORE_V13(ACC_INIT8)

#pragma unroll
  for (int ni = 0; ni < 4; ++ni) {
    const int gn = n0 + wn + ni * 16 + fr;
    const float bv = bias[gn];
#pragma unroll
    for (int mi = 0; mi < 8; ++mi) {
#pragma unroll
      for (int r = 0; r < 4; ++r) {
        const int gm = m0 + wm + mi * 16 + fq * 4 + r;
        float v = acc[mi][ni][r] + bv;
        v = v > 0.f ? v : 0.f;
        C[(size_t)gm * N + gn] = f_to_bf_raw(v);
      }
    }
  }
}

// ---------------------------------------------------------------------------
// Fused heads GEMM: relu(G @ WH^T + bias2048) dotted with w2cat in-register,
// non-atomic partials part[j][row], j = blockIdx.y*4 + (wave>>1) in [0,32).
// v13 core (verified best). Epilogue verified.
// ---------------------------------------------------------------------------
template <int K>
__global__ __launch_bounds__(512, 2) void gemm_heads_fused(
    const unsigned short* __restrict__ A,    // G row-major [B,1024]
    const unsigned short* __restrict__ Bf,   // WHf frag-major [2048,1024]
    const float* __restrict__ bias,          // bias2048
    const float* __restrict__ w2,            // w2cat
    float* __restrict__ part,                // [32][B_ROWS] (maybe row-offset)
    int M, int N) {
  GEMM_CORE_V13(ACC_INIT8)

  const int j = blockIdx.y * 4 + (wave >> 1);
  float w2v[4], bv[4];
#pragma unroll
  for (int ni = 0; ni < 4; ++ni) {
    const int gn = n0 + wn + ni * 16 + fr;
    w2v[ni] = w2[gn];
    bv[ni]  = bias[gn];
  }
#pragma unroll
  for (int mi = 0; mi < 8; ++mi) {
#pragma unroll
    for (int r = 0; r < 4; ++r) {
      float p = 0.f;
#pragma unroll
      for (int ni = 0; ni < 4; ++ni) {
        float v = acc[mi][ni][r] + bv[ni];
        v = v > 0.f ? v : 0.f;
        p += v * w2v[ni];
      }
      p += __shfl_xor(p, 1);
      p += __shfl_xor(p, 2);
      p += __shfl_xor(p, 4);
      p += __shfl_xor(p, 8);
      if (fr == 0) {
        const int gm = m0 + wm + mi * 16 + fq * 4 + r;
        part[(size_t)j * B_ROWS + gm] = p;
      }
    }
  }
}

// ---------------------------------------------------------------------------
// Final: sum partials, sigmoid, broadcast to out [3, B, 9]. 1 thread/row.
// ---------------------------------------------------------------------------
__global__ __launch_bounds__(256) void final_out(
    const float* __restrict__ part,
    const float* __restrict__ bc2, const float* __restrict__ bt2,
    const float* __restrict__ bk2, float* __restrict__ out) {
  const int row = blockIdx.x * 256 + threadIdx.x;
  float sc = 0.f, st = 0.f, sk = 0.f;
#pragma unroll
  for (int j = 0; j < 8; ++j)  sc += part[(size_t)j * B_ROWS + row];
#pragma unroll
  for (int j = 8; j < 16; ++j) st += part[(size_t)j * B_ROWS + row];
#pragma unroll
  for (int j = 16; j < 32; ++j) sk += part[(size_t)j * B_ROWS + row];
  const float cv = 1.f / (1.f + expf(-(sc + bc2[0])));
  const float tv = 1.f / (1.f + expf(-(st + bt2[0])));
  const float kv = 1.f / (1.f + expf(-(sk + bk2[0])));
  float* o0 = out + (size_t)row * N_AG;
  float* o1 = out + (size_t)(B_ROWS + row) * N_AG;
  float* o2 = out + (size_t)(2 * B_ROWS + row) * N_AG;
#pragma unroll
  for (int a = 0; a < N_AG; ++a) { o0[a] = cv; o1[a] = tv; o2[a] = kv; }
}

// ---------------------------------------------------------------------------
// Workspace plan (round-0 verified):
// FULL path (needs 70 MB + 16 KB):
//   [0,32MB)  slotA: obs_bf(16MB) + W1f(1MB @16MB)  --gemm2--> G(32MB)
//   [32,64MB) slotB: G1(32MB)                       --heads--> PART(2MB)
//   [64,66MB) W2f   [66,70MB) WHf   [70MB,+8KB) bias2048  [+8KB,+16KB) w2cat
// SPLIT path (ws_size < FULL_NEED; needs 57 MB + 16 KB): two 8192-row halves.
// ---------------------------------------------------------------------------
extern "C" void kernel_launch(void* const* d_in, const int* in_sizes, int n_in,
                              void* d_out, int out_size, void* d_ws, size_t ws_size,
                              hipStream_t stream) {
  const float* obs = (const float*)d_in[0];
  // d_in[1] agent_positions: unused (outputs don't depend on it)
  const float* W1  = (const float*)d_in[2];
  const float* b1  = (const float*)d_in[3];
  const float* W2  = (const float*)d_in[4];
  const float* b2  = (const float*)d_in[5];
  const float* Wc1 = (const float*)d_in[6];
  const float* bc1 = (const float*)d_in[7];
  const float* Wc2 = (const float*)d_in[8];
  const float* bc2 = (const float*)d_in[9];
  const float* Wt1 = (const float*)d_in[10];
  const float* bt1 = (const float*)d_in[11];
  const float* Wt2 = (const float*)d_in[12];
  const float* bt2 = (const float*)d_in[13];
  const float* Wk1 = (const float*)d_in[14];
  const float* bk1 = (const float*)d_in[15];
  const float* Wk2 = (const float*)d_in[16];
  const float* bk2 = (const float*)d_in[17];
  float* out = (float*)d_out;

  char* ws = (char*)d_ws;
  const size_t MB = 1024 * 1024;
  const size_t FULL_NEED = 70 * MB + 16 * 1024;

  unsigned short *obs_bf, *W1f, *W2f, *WHf, *G1, *G;
  float *bias2048, *w2cat, *PART;
  const bool full = (ws_size == 0) || (ws_size >= FULL_NEED);

  if (full) {
    obs_bf   = (unsigned short*)(ws + 0);
    W1f      = (unsigned short*)(ws + 16 * MB);
    G        = (unsigned short*)(ws + 0);        // alias: obs_bf+W1f dead
    G1       = (unsigned short*)(ws + 32 * MB);
    PART     = (float*)(ws + 32 * MB);           // alias: G1 dead
    W2f      = (unsigned short*)(ws + 64 * MB);
    WHf      = (unsigned short*)(ws + 66 * MB);
    bias2048 = (float*)(ws + 70 * MB);
    w2cat    = (float*)(ws + 70 * MB + 8 * 1024);
  } else {
    obs_bf   = (unsigned short*)(ws + 0);        // 16 MB, full B
    G1       = (unsigned short*)(ws + 16 * MB);  // 16 MB (half)
    G        = (unsigned short*)(ws + 32 * MB);  // 16 MB (half)
    W1f      = (unsigned short*)(ws + 48 * MB);
    W2f      = (unsigned short*)(ws + 49 * MB);
    WHf      = (unsigned short*)(ws + 51 * MB);
    bias2048 = (float*)(ws + 55 * MB);
    w2cat    = (float*)(ws + 55 * MB + 8 * 1024);
    PART     = (float*)(ws + 55 * MB + 16 * 1024); // 2 MB, full B
  }

  prep_all<<<7688, 256, 0, stream>>>(obs, W1, W2, Wc1, Wt1, Wk1,
                                     bc1, bt1, bk1, Wc2, Wt2, Wk2,
                                     obs_bf, W1f, W2f, WHf, bias2048, w2cat);

  if (full) {
    gemm_bias_relu<512><<<dim3(128, 8), 256, 0, stream>>>(
        obs_bf, W1f, b1, G1, B_ROWS, 1024);
    gemm_bias_relu_v13<1024><<<dim3(64, 4), 512, 0, stream>>>(
        G1, W2f, b2, G, B_ROWS, 1024);
    gemm_heads_fused<1024><<<dim3(64, 8), 512, 0, stream>>>(
        G, WHf, bias2048, w2cat, PART, B_ROWS, 2048);
  } else {
    for (int h = 0; h < 2; ++h) {
      const size_t ro = (size_t)h * 8192;
      gemm_bias_relu<512><<<dim3(64, 8), 256, 0, stream>>>(
          obs_bf + ro * 512, W1f, b1, G1, 8192, 1024);
      gemm_bias_relu_v13<1024><<<dim3(32, 4), 512, 0, stream>>>(
          G1, W2f, b2, G, 8192, 1024);
      gemm_heads_fused<1024><<<dim3(32, 8), 512, 0, stream>>>(
          G, WHf, bias2048, w2cat, PART + ro, 8192, 2048);
    }
  }

  final_out<<<B_ROWS / 256, 256, 0, stream>>>(PART, bc2, bt2, bk2, out);
}

// Round 14
// 244.313 us; speedup vs baseline: 1.0148x; 1.0075x over previous
//
#include <hip/hip_runtime.h>
#include <hip/hip_bf16.h>

// Problem constants
#define B_ROWS 16384
#define OBS_D  512
#define H_D    1024
#define N_AG   9

typedef __attribute__((ext_vector_type(8))) short short8;
typedef __attribute__((ext_vector_type(4))) float floatx4;

__device__ __forceinline__ unsigned short f_to_bf_raw(float f) {
  union { float f; unsigned u; } c; c.f = f;
  unsigned u = c.u;
  u = u + 0x7FFF + ((u >> 16) & 1);   // round-to-nearest-even
  return (unsigned short)(u >> 16);
}

// Fragment-major WEIGHT layout (B operand only; A stays row-major):
//   frag_tile = (n>>4)*KT32 + (k>>5)
//   lane      = (n&15) | (((k>>3)&3)<<4)
//   j         = k&7
// offset (bf16 units) = (frag_tile*64 + lane)*8 + j
__device__ __forceinline__ size_t frag_off(int n, int k, int KT32) {
  const int ft = (n >> 4) * KT32 + (k >> 5);
  const int ln = (n & 15) | (((k >> 3) & 3) << 4);
  return ((size_t)ft * 64 + ln) * 8 + (k & 7);
}

// ---------------------------------------------------------------------------
// Mega-prep (proven, unchanged)
// ---------------------------------------------------------------------------
__global__ __launch_bounds__(256) void prep_all(
    const float* __restrict__ obs,
    const float* __restrict__ W1, const float* __restrict__ W2,
    const float* __restrict__ Wc1, const float* __restrict__ Wt1,
    const float* __restrict__ Wk1,
    const float* __restrict__ bc1, const float* __restrict__ bt1,
    const float* __restrict__ bk1,
    const float* __restrict__ Wc2, const float* __restrict__ Wt2,
    const float* __restrict__ Wk2,
    unsigned short* __restrict__ obs_bf,
    unsigned short* __restrict__ W1f, unsigned short* __restrict__ W2f,
    unsigned short* __restrict__ WHf,
    float* __restrict__ bias2048, float* __restrict__ w2cat) {
  __shared__ float t[32][33];
  const int bx  = blockIdx.x;
  const int tid = threadIdx.x;

  if (bx < 4096) {                       // obs fp32 -> bf16, 8 elems/thread
    int i = (bx * 256 + tid) * 8;
    float4 a = *(const float4*)(obs + i);
    float4 b = *(const float4*)(obs + i + 4);
    short8 o;
    o[0] = (short)f_to_bf_raw(a.x); o[1] = (short)f_to_bf_raw(a.y);
    o[2] = (short)f_to_bf_raw(a.z); o[3] = (short)f_to_bf_raw(a.w);
    o[4] = (short)f_to_bf_raw(b.x); o[5] = (short)f_to_bf_raw(b.y);
    o[6] = (short)f_to_bf_raw(b.z); o[7] = (short)f_to_bf_raw(b.w);
    *(short8*)(obs_bf + i) = o;
    return;
  }

  const int tx = tid & 31;
  const int ty = tid >> 5;   // 0..7

  if (bx < 4608) {                       // W1 [512,1024] -> W1f (K=512,KT32=16)
    const int tt = bx - 4096;
    const int k0 = (tt & 15) * 32;
    const int n0 = (tt >> 4) * 32;
#pragma unroll
    for (int i = ty; i < 32; i += 8)
      t[i][tx] = W1[(size_t)(k0 + i) * 1024 + n0 + tx];
    __syncthreads();
#pragma unroll
    for (int i = ty; i < 32; i += 8)
      W1f[frag_off(n0 + i, k0 + tx, 16)] = f_to_bf_raw(t[tx][i]);
    return;
  }

  if (bx < 5632) {                       // W2 [1024,1024] -> W2f (KT32=32)
    const int tt = bx - 4608;
    const int k0 = (tt & 31) * 32;
    const int n0 = (tt >> 5) * 32;
#pragma unroll
    for (int i = ty; i < 32; i += 8)
      t[i][tx] = W2[(size_t)(k0 + i) * 1024 + n0 + tx];
    __syncthreads();
#pragma unroll
    for (int i = ty; i < 32; i += 8)
      W2f[frag_off(n0 + i, k0 + tx, 32)] = f_to_bf_raw(t[tx][i]);
    return;
  }

  if (bx < 7680) {                       // WHf [2048 n,1024 k] (KT32=32)
    const int tt = bx - 5632;
    const int k0 = (tt & 31) * 32;
    const int n0 = (tt >> 5) * 32;       // region-uniform per block
#pragma unroll
    for (int i = ty; i < 32; i += 8) {
      const int n = n0 + tx;
      float v;
      if (n0 < 512)
        v = Wc1[(size_t)(k0 + i) * 512 + n];
      else if (n0 < 1024)
        v = Wt1[(size_t)(k0 + i) * 512 + (n - 512)];
      else
        v = Wk1[(size_t)(k0 + i) * 1024 + (n - 1024)]
          + Wk1[(size_t)(k0 + i + 1024) * 1024 + (n - 1024)];
      t[i][tx] = v;
    }
    __syncthreads();
#pragma unroll
    for (int i = ty; i < 32; i += 8)
      WHf[frag_off(n0 + i, k0 + tx, 32)] = f_to_bf_raw(t[tx][i]);
    return;
  }

  {                                      // bias2048 / w2cat
    int n = (bx - 7680) * 256 + tid;
    float b, w;
    if (n < 512)       { b = bc1[n];        w = Wc2[n]; }
    else if (n < 1024) { b = bt1[n - 512];  w = Wt2[n - 512]; }
    else               { b = bk1[n - 1024]; w = Wk2[n - 1024]; }
    bias2048[n] = b;
    w2cat[n] = w;
  }
}

#define GLD_LDS(gp, lp)                                                        \
  __builtin_amdgcn_global_load_lds(                                            \
      (const __attribute__((address_space(1))) void*)(gp),                     \
      (__attribute__((address_space(3))) void*)(lp), 16, 0, 0)

#define SCB __builtin_amdgcn_sched_barrier(0)

#define MFMA_BF16(a, b, c) __builtin_amdgcn_mfma_f32_16x16x32_bf16(a, b, c, 0, 0, 0)

// ===========================================================================
// GEMM core v9 (HW-verified best for gemm1/gemm2): 128x128 tile, BK=64,
// 4 waves, 48KB LDS (~2-3 blk/CU), one __syncthreads per K-step.
// Cross-block overlap (m114) hides the serialized phases at this occupancy.
// ===========================================================================
#define GEMM_CORE_V9(ACC_DECL)                                                 \
  __shared__ __align__(16) unsigned short As[3][128 * 64];  /* 48 KB */        \
  const int tid  = threadIdx.x;                                                \
  const int lane = tid & 63;                                                   \
  const int wave = tid >> 6;                                                   \
  const int m0 = blockIdx.x * 128;                                             \
  const int n0 = blockIdx.y * 128;                                             \
  const int wm = (wave & 1) * 64;                                              \
  const int wn = (wave >> 1) * 64;                                             \
  const int fr = lane & 15;                                                    \
  const int fq = lane >> 4;                                                    \
  ACC_DECL;                                                                    \
  constexpr int KT   = K >> 6;     /* BK=64 iterations      */                 \
  constexpr int KT32 = K >> 5;     /* 32-wide k-tiles (B)   */                 \
  const size_t rowb = (size_t)K * 2;                                           \
  const int srow8  = lane >> 3;                 /* 0..7 row in 8-row group */  \
  const int schunk = (lane & 7) ^ srow8;        /* swizzled global chunk   */  \
  const char* gA = (const char*)A + (size_t)(m0 + wave * 32 + srow8) * rowb    \
                   + schunk * 16;                                              \
  char* lA = (char*)&As[0][0] + wave * 4096 + lane * 16;                       \
  const unsigned short* gB =                                                   \
      Bf + ((size_t)(((n0 + wn) >> 4) * KT32) * 64 + lane) * 8;                \
  const int fsA = (wm + fr) * 128;                                             \
  const int sl0 = ((fq)     ^ (fr & 7)) * 16;                                  \
  const int sl1 = ((4 + fq) ^ (fr & 7)) * 16;                                  \
  short8 FbP[2][2][4];                                                         \
  _Pragma("unroll")                                                            \
  for (int j = 0; j < 4; ++j)                                                  \
    GLD_LDS(gA + (size_t)j * 8 * rowb, lA + j * 1024);                         \
  _Pragma("unroll")                                                            \
  for (int j = 0; j < 4; ++j)                                                  \
    GLD_LDS(gA + 128 + (size_t)j * 8 * rowb,                                   \
            (char*)&As[1][0] + wave * 4096 + lane * 16 + j * 1024);            \
  _Pragma("unroll")                                                            \
  for (int s = 0; s < 2; ++s)                                                  \
    _Pragma("unroll")                                                          \
    for (int ni = 0; ni < 4; ++ni)                                             \
      FbP[0][s][ni] = *(const short8*)(gB + ((size_t)ni * KT32 + s) * 512);    \
  _Pragma("unroll")                                                            \
  for (int k = 0; k < KT; ++k) {       /* constexpr bound -> full unroll */    \
    __syncthreads();   /* drains DMA(k+1) (one full iter in flight) */         \
    if (k + 2 < KT) {                                                          \
      char* d = (char*)&As[(k + 2) % 3][0] + wave * 4096 + lane * 16;          \
      const char* g = gA + (size_t)(k + 2) * 128;                              \
      _Pragma("unroll")                                                        \
      for (int j = 0; j < 4; ++j)                                              \
        GLD_LDS(g + (size_t)j * 8 * rowb, d + j * 1024);                       \
    }                                                                          \
    if (k + 1 < KT) {                                                          \
      _Pragma("unroll")                                                        \
      for (int s = 0; s < 2; ++s)                                              \
        _Pragma("unroll")                                                      \
        for (int ni = 0; ni < 4; ++ni)                                         \
          FbP[(k + 1) & 1][s][ni] = *(const short8*)                           \
              (gB + ((size_t)ni * KT32 + 2 * (k + 1) + s) * 512);              \
    }                                                                          \
    const char* bA = (const char*)&As[k % 3][0];                               \
    short8 Fa0[4], Fa1[4];                                                     \
    _Pragma("unroll")                                                          \
    for (int mi = 0; mi < 4; ++mi)                                             \
      Fa0[mi] = *(const short8*)(bA + fsA + mi * 2048 + sl0);                  \
    _Pragma("unroll")                                                          \
    for (int mi = 0; mi < 4; ++mi)                                             \
      Fa1[mi] = *(const short8*)(bA + fsA + mi * 2048 + sl1);                  \
    _Pragma("unroll")                                                          \
    for (int mi = 0; mi < 4; ++mi)                                             \
      _Pragma("unroll")                                                        \
      for (int ni = 0; ni < 4; ++ni)                                           \
        acc[mi][ni] = __builtin_amdgcn_mfma_f32_16x16x32_bf16(                 \
            Fa0[mi], FbP[k & 1][0][ni], acc[mi][ni], 0, 0, 0);                 \
    _Pragma("unroll")                                                          \
    for (int mi = 0; mi < 4; ++mi)                                             \
      _Pragma("unroll")                                                        \
      for (int ni = 0; ni < 4; ++ni)                                           \
        acc[mi][ni] = __builtin_amdgcn_mfma_f32_16x16x32_bf16(                 \
            Fa1[mi], FbP[k & 1][1][ni], acc[mi][ni], 0, 0, 0);                 \
  }

#define ACC_INIT4                                                              \
  floatx4 acc[4][4];                                                           \
  _Pragma("unroll")                                                            \
  for (int i = 0; i < 4; ++i)                                                  \
    _Pragma("unroll")                                                          \
    for (int j = 0; j < 4; ++j) acc[i][j] = (floatx4){0.f, 0.f, 0.f, 0.f}

// ===========================================================================
// GEMM core v13 (HW-verified best for heads, R7/R12: 68.6-70.5us / ~1000 TF
// / 0 conflicts): 256x256 tile, BK=64, 8 waves, 128KB LDS, 4-phase schedule
// (T3), counted vmcnt once per K-tile (T4), setprio (T5), A-LDS XOR
// swizzle (T2: global chunk (lane&3)^((lane>>3)&3), read fq^((fr>>1)&3)).
// R13 lesson: do NOT instantiate this core for gemm2 in the same build —
// heads degraded 70.5->94us (rule #19 co-compilation / power coupling).
// ===========================================================================
#define ST_A(T, kh)                                                            \
  GLD_LDS(gA0 + (size_t)(T) * 128 + (kh) * 64,                                 \
          Lds + ((T) & 1) * 65536 + (kh) * 16384 + lA0);                       \
  GLD_LDS(gA1 + (size_t)(T) * 128 + (kh) * 64,                                 \
          Lds + ((T) & 1) * 65536 + (kh) * 16384 + lA0 + 8192)

#define ST_B(T, kh)                                                            \
  GLD_LDS(gB0 + (size_t)(2 * (T) + (kh)) * 1024,                               \
          Lds + ((T) & 1) * 65536 + (kh) * 16384 + lB0);                       \
  GLD_LDS(gB1 + (size_t)(2 * (T) + (kh)) * 1024,                               \
          Lds + ((T) & 1) * 65536 + (kh) * 16384 + lB0 + 8192)

#define FB4(pb)                                                                \
  Fb[0] = *(const short8*)((pb) + fbB);                                        \
  Fb[1] = *(const short8*)((pb) + fbB + 1024);                                 \
  Fb[2] = *(const short8*)((pb) + fbB + 2048);                                 \
  Fb[3] = *(const short8*)((pb) + fbB + 3072)

#define MFMA16(mh)                                                             \
  acc[(mh)*4+0][0] = MFMA_BF16(Fa0, Fb[0], acc[(mh)*4+0][0]);                  \
  acc[(mh)*4+0][1] = MFMA_BF16(Fa0, Fb[1], acc[(mh)*4+0][1]);                  \
  acc[(mh)*4+0][2] = MFMA_BF16(Fa0, Fb[2], acc[(mh)*4+0][2]);                  \
  acc[(mh)*4+0][3] = MFMA_BF16(Fa0, Fb[3], acc[(mh)*4+0][3]);                  \
  acc[(mh)*4+1][0] = MFMA_BF16(Fa1, Fb[0], acc[(mh)*4+1][0]);                  \
  acc[(mh)*4+1][1] = MFMA_BF16(Fa1, Fb[1], acc[(mh)*4+1][1]);                  \
  acc[(mh)*4+1][2] = MFMA_BF16(Fa1, Fb[2], acc[(mh)*4+1][2]);                  \
  acc[(mh)*4+1][3] = MFMA_BF16(Fa1, Fb[3], acc[(mh)*4+1][3]);                  \
  acc[(mh)*4+2][0] = MFMA_BF16(Fa2, Fb[0], acc[(mh)*4+2][0]);                  \
  acc[(mh)*4+2][1] = MFMA_BF16(Fa2, Fb[1], acc[(mh)*4+2][1]);                  \
  acc[(mh)*4+2][2] = MFMA_BF16(Fa2, Fb[2], acc[(mh)*4+2][2]);                  \
  acc[(mh)*4+2][3] = MFMA_BF16(Fa2, Fb[3], acc[(mh)*4+2][3]);                  \
  acc[(mh)*4+3][0] = MFMA_BF16(Fa3, Fb[0], acc[(mh)*4+3][0]);                  \
  acc[(mh)*4+3][1] = MFMA_BF16(Fa3, Fb[1], acc[(mh)*4+3][1]);                  \
  acc[(mh)*4+3][2] = MFMA_BF16(Fa3, Fb[2], acc[(mh)*4+3][2]);                  \
  acc[(mh)*4+3][3] = MFMA_BF16(Fa3, Fb[3], acc[(mh)*4+3][3])

#define PHASE(TT, ks, mh, EXTRA_READS, STAGE_STMT, PRE_BAR2)                   \
  {                                                                            \
    const char* pb = Lds + ((TT) & 1) * 65536 + (ks) * 16384;                  \
    short8 Fa0 = *(const short8*)(pb + faB + ((mh)*4+0)*1024);                 \
    short8 Fa1 = *(const short8*)(pb + faB + ((mh)*4+1)*1024);                 \
    short8 Fa2 = *(const short8*)(pb + faB + ((mh)*4+2)*1024);                 \
    short8 Fa3 = *(const short8*)(pb + faB + ((mh)*4+3)*1024);                 \
    EXTRA_READS;                                                               \
    STAGE_STMT;                                                                \
    SCB; __builtin_amdgcn_s_barrier(); SCB;                                    \
    __builtin_amdgcn_s_setprio(1);                                             \
    MFMA16(mh);                                                                \
    __builtin_amdgcn_s_setprio(0);                                             \
    PRE_BAR2;                                                                  \
    SCB; __builtin_amdgcn_s_barrier(); SCB;                                    \
  }

#define GEMM_CORE_V13(ACC_DECL)                                                \
  __shared__ __align__(16) char Lds[131072];                                   \
  const int tid  = threadIdx.x;                                                \
  const int lane = tid & 63;                                                   \
  const int wave = tid >> 6;           /* 0..7 */                              \
  const int m0 = blockIdx.x * 256;                                             \
  const int n0 = blockIdx.y * 256;                                             \
  const int wm = (wave & 1) * 128;     /* 2 M-waves x 4 N-waves */             \
  const int wn = (wave >> 1) * 64;                                             \
  const int fr = lane & 15;                                                    \
  const int fq = lane >> 4;                                                    \
  ACC_DECL;                                                                    \
  constexpr int KT   = K >> 6;                                                 \
  constexpr int KT32 = K >> 5;                                                 \
  const size_t rowb = (size_t)K * 2;                                           \
  const char* gA0 = (const char*)A                                             \
      + (size_t)(m0 + wave * 16 + (lane >> 2)) * rowb                          \
      + (((lane & 3) ^ ((lane >> 3) & 3)) * 16);                               \
  const char* gA1 = gA0 + (size_t)128 * rowb;                                  \
  const char* gB0 = (const char*)Bf                                            \
      + ((size_t)((n0 >> 4) + wave) * KT32) * 1024 + lane * 16;                \
  const char* gB1 = gB0 + (size_t)8 * KT32 * 1024;                             \
  const int lA0 = wave * 1024 + lane * 16;                                     \
  const int lB0 = 32768 + wave * 1024 + lane * 16;                             \
  const int faB = (wm + fr) * 64 + ((fq ^ ((fr >> 1) & 3)) * 16);              \
  const int fbB = 32768 + ((wave >> 1) * 4) * 1024 + lane * 16;                \
  short8 Fb[4];                                                                \
  /* prologue: T0 full (8 DMAs) + T1 kh0 (4 DMAs); order pinned */             \
  ST_A(0, 0); ST_B(0, 0); ST_A(0, 1); ST_B(0, 1);                              \
  SCB;                                                                         \
  ST_A(1, 0); ST_B(1, 0);                                                      \
  SCB;                                                                         \
  asm volatile("s_waitcnt vmcnt(4)" ::: "memory");  /* T0 landed (mine) */     \
  __builtin_amdgcn_s_barrier();        /* -> T0 landed (all waves) */          \
  SCB;                                                                         \
  _Pragma("unroll")                                                            \
  for (int T = 0; T < KT; ++T) {       /* constexpr bound -> full unroll */    \
    PHASE(T, 0, 0, FB4(pb), if (T + 1 < KT) { ST_A(T + 1, 1); }, (void)0);     \
    PHASE(T, 0, 1, (void)0, if (T + 1 < KT) { ST_B(T + 1, 1); }, (void)0);     \
    PHASE(T, 1, 0, FB4(pb), if (T + 2 < KT) { ST_A(T + 2, 0); }, (void)0);     \
    PHASE(T, 1, 1, (void)0, if (T + 2 < KT) { ST_B(T + 2, 0); },               \
          if (T + 1 < KT) {                                                    \
            SCB;                                                               \
            if (T + 2 < KT) {                                                  \
              asm volatile("s_waitcnt vmcnt(4)" ::: "memory");                 \
            } else {                                                           \
              asm volatile("s_waitcnt vmcnt(0)" ::: "memory");                 \
            }                                                                  \
            SCB;                                                               \
          });                                                                  \
  }

#define ACC_INIT8                                                              \
  floatx4 acc[8][4];                                                           \
  _Pragma("unroll")                                                            \
  for (int i = 0; i < 8; ++i)                                                  \
    _Pragma("unroll")                                                          \
    for (int j = 0; j < 4; ++j) acc[i][j] = (floatx4){0.f, 0.f, 0.f, 0.f}

// ---------------------------------------------------------------------------
// GEMM: C = relu(A @ B^T + bias), bf16 out (row-major). v9 core (verified).
// ---------------------------------------------------------------------------
template <int K>
__global__ __launch_bounds__(256, 2) void gemm_bias_relu(
    const unsigned short* __restrict__ A,
    const unsigned short* __restrict__ Bf,
    const float* __restrict__ bias,
    unsigned short* __restrict__ C,
    int M, int N) {
  GEMM_CORE_V9(ACC_INIT4)

  // Epilogue: C/D layout col=lane&15, row=(lane>>4)*4+reg
#pragma unroll
  for (int ni = 0; ni < 4; ++ni) {
    const int gn = n0 + wn + ni * 16 + fr;
    const float bv = bias[gn];
#pragma unroll
    for (int mi = 0; mi < 4; ++mi) {
#pragma unroll
      for (int r = 0; r < 4; ++r) {
        const int gm = m0 + wm + mi * 16 + fq * 4 + r;
        float v = acc[mi][ni][r] + bv;
        v = v > 0.f ? v : 0.f;
        C[(size_t)gm * N + gn] = f_to_bf_raw(v);
      }
    }
  }
}

// ---------------------------------------------------------------------------
// Fused heads GEMM: relu(G @ WH^T + bias2048) dotted with w2cat in-register,
// non-atomic partials part[j][row], j = blockIdx.y*4 + (wave>>1) in [0,32).
// v13 core (verified best). Epilogue verified.
// ---------------------------------------------------------------------------
template <int K>
__global__ __launch_bounds__(512, 2) void gemm_heads_fused(
    const unsigned short* __restrict__ A,    // G row-major [B,1024]
    const unsigned short* __restrict__ Bf,   // WHf frag-major [2048,1024]
    const float* __restrict__ bias,          // bias2048
    const float* __restrict__ w2,            // w2cat
    float* __restrict__ part,                // [32][B_ROWS] (maybe row-offset)
    int M, int N) {
  GEMM_CORE_V13(ACC_INIT8)

  const int j = blockIdx.y * 4 + (wave >> 1);
  float w2v[4], bv[4];
#pragma unroll
  for (int ni = 0; ni < 4; ++ni) {
    const int gn = n0 + wn + ni * 16 + fr;
    w2v[ni] = w2[gn];
    bv[ni]  = bias[gn];
  }
#pragma unroll
  for (int mi = 0; mi < 8; ++mi) {
#pragma unroll
    for (int r = 0; r < 4; ++r) {
      float p = 0.f;
#pragma unroll
      for (int ni = 0; ni < 4; ++ni) {
        float v = acc[mi][ni][r] + bv[ni];
        v = v > 0.f ? v : 0.f;
        p += v * w2v[ni];
      }
      p += __shfl_xor(p, 1);
      p += __shfl_xor(p, 2);
      p += __shfl_xor(p, 4);
      p += __shfl_xor(p, 8);
      if (fr == 0) {
        const int gm = m0 + wm + mi * 16 + fq * 4 + r;
        part[(size_t)j * B_ROWS + gm] = p;
      }
    }
  }
}

// ---------------------------------------------------------------------------
// Final: sum partials, sigmoid, broadcast to out [3, B, 9]. 1 thread/row.
// ---------------------------------------------------------------------------
__global__ __launch_bounds__(256) void final_out(
    const float* __restrict__ part,
    const float* __restrict__ bc2, const float* __restrict__ bt2,
    const float* __restrict__ bk2, float* __restrict__ out) {
  const int row = blockIdx.x * 256 + threadIdx.x;
  float sc = 0.f, st = 0.f, sk = 0.f;
#pragma unroll
  for (int j = 0; j < 8; ++j)  sc += part[(size_t)j * B_ROWS + row];
#pragma unroll
  for (int j = 8; j < 16; ++j) st += part[(size_t)j * B_ROWS + row];
#pragma unroll
  for (int j = 16; j < 32; ++j) sk += part[(size_t)j * B_ROWS + row];
  const float cv = 1.f / (1.f + expf(-(sc + bc2[0])));
  const float tv = 1.f / (1.f + expf(-(st + bt2[0])));
  const float kv = 1.f / (1.f + expf(-(sk + bk2[0])));
  float* o0 = out + (size_t)row * N_AG;
  float* o1 = out + (size_t)(B_ROWS + row) * N_AG;
  float* o2 = out + (size_t)(2 * B_ROWS + row) * N_AG;
#pragma unroll
  for (int a = 0; a < N_AG; ++a) { o0[a] = cv; o1[a] = tv; o2[a] = kv; }
}

// ---------------------------------------------------------------------------
// Workspace plan (round-0 verified):
// FULL path (needs 70 MB + 16 KB):
//   [0,32MB)  slotA: obs_bf(16MB) + W1f(1MB @16MB)  --gemm2--> G(32MB)
//   [32,64MB) slotB: G1(32MB)                       --heads--> PART(2MB)
//   [64,66MB) W2f   [66,70MB) WHf   [70MB,+8KB) bias2048  [+8KB,+16KB) w2cat
// SPLIT path (ws_size < FULL_NEED; needs 57 MB + 16 KB): two 8192-row halves.
// ---------------------------------------------------------------------------
extern "C" void kernel_launch(void* const* d_in, const int* in_sizes, int n_in,
                              void* d_out, int out_size, void* d_ws, size_t ws_size,
                              hipStream_t stream) {
  const float* obs = (const float*)d_in[0];
  // d_in[1] agent_positions: unused (outputs don't depend on it)
  const float* W1  = (const float*)d_in[2];
  const float* b1  = (const float*)d_in[3];
  const float* W2  = (const float*)d_in[4];
  const float* b2  = (const float*)d_in[5];
  const float* Wc1 = (const float*)d_in[6];
  const float* bc1 = (const float*)d_in[7];
  const float* Wc2 = (const float*)d_in[8];
  const float* bc2 = (const float*)d_in[9];
  const float* Wt1 = (const float*)d_in[10];
  const float* bt1 = (const float*)d_in[11];
  const float* Wt2 = (const float*)d_in[12];
  const float* bt2 = (const float*)d_in[13];
  const float* Wk1 = (const float*)d_in[14];
  const float* bk1 = (const float*)d_in[15];
  const float* Wk2 = (const float*)d_in[16];
  const float* bk2 = (const float*)d_in[17];
  float* out = (float*)d_out;

  char* ws = (char*)d_ws;
  const size_t MB = 1024 * 1024;
  const size_t FULL_NEED = 70 * MB + 16 * 1024;

  unsigned short *obs_bf, *W1f, *W2f, *WHf, *G1, *G;
  float *bias2048, *w2cat, *PART;
  const bool full = (ws_size == 0) || (ws_size >= FULL_NEED);

  if (full) {
    obs_bf   = (unsigned short*)(ws + 0);
    W1f      = (unsigned short*)(ws + 16 * MB);
    G        = (unsigned short*)(ws + 0);        // alias: obs_bf+W1f dead
    G1       = (unsigned short*)(ws + 32 * MB);
    PART     = (float*)(ws + 32 * MB);           // alias: G1 dead
    W2f      = (unsigned short*)(ws + 64 * MB);
    WHf      = (unsigned short*)(ws + 66 * MB);
    bias2048 = (float*)(ws + 70 * MB);
    w2cat    = (float*)(ws + 70 * MB + 8 * 1024);
  } else {
    obs_bf   = (unsigned short*)(ws + 0);        // 16 MB, full B
    G1       = (unsigned short*)(ws + 16 * MB);  // 16 MB (half)
    G        = (unsigned short*)(ws + 32 * MB);  // 16 MB (half)
    W1f      = (unsigned short*)(ws + 48 * MB);
    W2f      = (unsigned short*)(ws + 49 * MB);
    WHf      = (unsigned short*)(ws + 51 * MB);
    bias2048 = (float*)(ws + 55 * MB);
    w2cat    = (float*)(ws + 55 * MB + 8 * 1024);
    PART     = (float*)(ws + 55 * MB + 16 * 1024); // 2 MB, full B
  }

  prep_all<<<7688, 256, 0, stream>>>(obs, W1, W2, Wc1, Wt1, Wk1,
                                     bc1, bt1, bk1, Wc2, Wt2, Wk2,
                                     obs_bf, W1f, W2f, WHf, bias2048, w2cat);

  if (full) {
    gemm_bias_relu<512><<<dim3(128, 8), 256, 0, stream>>>(
        obs_bf, W1f, b1, G1, B_ROWS, 1024);
    gemm_bias_relu<1024><<<dim3(128, 8), 256, 0, stream>>>(
        G1, W2f, b2, G, B_ROWS, 1024);
    gemm_heads_fused<1024><<<dim3(64, 8), 512, 0, stream>>>(
        G, WHf, bias2048, w2cat, PART, B_ROWS, 2048);
  } else {
    for (int h = 0; h < 2; ++h) {
      const size_t ro = (size_t)h * 8192;
      gemm_bias_relu<512><<<dim3(64, 8), 256, 0, stream>>>(
          obs_bf + ro * 512, W1f, b1, G1, 8192, 1024);
      gemm_bias_relu<1024><<<dim3(64, 8), 256, 0, stream>>>(
          G1, W2f, b2, G, 8192, 1024);
      gemm_heads_fused<1024><<<dim3(32, 8), 512, 0, stream>>>(
          G, WHf, bias2048, w2cat, PART + ro, 8192, 2048);
    }
  }

  final_out<<<B_ROWS / 256, 256, 0, stream>>>(PART, bc2, bt2, bk2, out);
}